// Round 12
// baseline (3333.650 us; speedup 1.0000x reference)
//
#include <hip/hip_runtime.h>
#include <hip/hip_bf16.h>
#include <cstdint>
#include <cstddef>

// B=32, T=512, I=H=1024, L=2, gates 4H=4096. fp32 in/out.
// d_out fp32: outputs[32][512][1024] ++ h_n[2][32][1024] ++ c_n[2][32][1024].
// Per chunk of Tc steps:
//   gemm128: G0 = x@Wx0^T + b0 (bf16 MFMA, fp32 out; Wx0 pre-cast bf16)
//   lstm_persist (cooperative, 160 blocks, flag-sync, no grid.sync):
//     blocks   0..63 : L0 recurrence (16 cols x 4 gates, K=1024)
//     blocks  64..127: P-blocks: P[t] = W1h0 . h0[t], pipelined ~8 ahead
//     blocks 128..159: L1 critical loop, 32 cols/block, wave-self-contained:
//                      each wave = 4 cols x 4 gates x full K=1024 (no pg
//                      exchange, no K-split barrier); gate transpose via
//                      4x4 shfl butterfly; gates = bias + P(dwordx4) + acc.
//     16B sc1 ring transfers, per-block flags, weights pinned in regs.

typedef unsigned short ush;
typedef short bf16x8 __attribute__((ext_vector_type(8)));
typedef float f32x4 __attribute__((ext_vector_type(4)));
typedef int i32x4 __attribute__((ext_vector_type(4)));
typedef int i32x2 __attribute__((ext_vector_type(2)));
typedef unsigned long long u64;

#define TT 512
#define NA 64
#define RING 8

__device__ __forceinline__ ush f2bf(float f) {
  __hip_bfloat16 h = __float2bfloat16(f);
  return *reinterpret_cast<ush*>(&h);
}
__device__ __forceinline__ float sigm(float x) { return 1.f / (1.f + __expf(-x)); }

__device__ __forceinline__ unsigned int aload(const unsigned int* p) {
  return __hip_atomic_load(p, __ATOMIC_RELAXED, __HIP_MEMORY_SCOPE_AGENT);
}
__device__ __forceinline__ void astore(unsigned int* p, unsigned int v) {
  __hip_atomic_store(p, v, __ATOMIC_RELAXED, __HIP_MEMORY_SCOPE_AGENT);
}

// ---------------------------------------------------------------------------
// Wb[j][k] = bf16(W[j][off+k]), 1024 cols (plain layout, for gemm128 B).
// ---------------------------------------------------------------------------
__global__ __launch_bounds__(256) void cast_w1k(const float* __restrict__ W,
                                                ush* __restrict__ Wb, int off) {
  int j = blockIdx.x;
  int k = threadIdx.x * 4;
  float4 v = *(const float4*)(W + (size_t)j * 2048 + off + k);
  ushort4 o;
  o.x = f2bf(v.x); o.y = f2bf(v.y); o.z = f2bf(v.z); o.w = f2bf(v.w);
  *(ushort4*)(Wb + (size_t)j * 1024 + k) = o;
}

// ---------------------------------------------------------------------------
// L0-style pre-swizzle: 64 blocks x 16 cols x 4 gates, K=1024 at col coloff.
// n < 524288. lane=n&63, ch=(n>>6)&15, w=(n>>10)&7, i=n>>13.
// ---------------------------------------------------------------------------
__global__ __launch_bounds__(256) void swzW(const float* __restrict__ W,
                                            ush* __restrict__ D, int coloff) {
  int n = blockIdx.x * 256 + threadIdx.x;
  int lane = n & 63, ch = (n >> 6) & 15, w = (n >> 10) & 7, i = n >> 13;
  int l15 = lane & 15, quad = lane >> 4, g = w & 3, kh = w >> 2;
  int row = g * 1024 + i * 16 + l15;
  int col = coloff + kh * 512 + ch * 32 + quad * 8;
  const float* src = W + (size_t)row * 2048 + col;
  float4 v0 = ((const float4*)src)[0];
  float4 v1 = ((const float4*)src)[1];
  ushort4 o0, o1;
  o0.x = f2bf(v0.x); o0.y = f2bf(v0.y); o0.z = f2bf(v0.z); o0.w = f2bf(v0.w);
  o1.x = f2bf(v1.x); o1.y = f2bf(v1.y); o1.z = f2bf(v1.z); o1.w = f2bf(v1.w);
  *(ushort4*)(D + (size_t)n * 8) = o0;
  *(ushort4*)(D + (size_t)n * 8 + 4) = o1;
}

// ---------------------------------------------------------------------------
// W1 h1-half pre-swizzle for 32 fat L1 blocks: wave w of block jb owns rows
// {g*1024 + jb*32 + w*4 + c : g in [0,4), c in [0,4)}, full K=1024 (col 1024+).
// n < 524288: lane=n&63, ch=(n>>6)&31, w=(n>>11)&7, jb=n>>14.
// ---------------------------------------------------------------------------
__global__ __launch_bounds__(256) void swz1n(const float* __restrict__ W,
                                             ush* __restrict__ D) {
  int n = blockIdx.x * 256 + threadIdx.x;
  int lane = n & 63, ch = (n >> 6) & 31, w = (n >> 11) & 7, jb = n >> 14;
  int l15 = lane & 15, quad = lane >> 4;
  int row = (l15 >> 2) * 1024 + jb * 32 + w * 4 + (l15 & 3);
  int col = 1024 + ch * 32 + quad * 8;
  const float* src = W + (size_t)row * 2048 + col;
  float4 v0 = ((const float4*)src)[0];
  float4 v1 = ((const float4*)src)[1];
  ushort4 o0, o1;
  o0.x = f2bf(v0.x); o0.y = f2bf(v0.y); o0.z = f2bf(v0.z); o0.w = f2bf(v0.w);
  o1.x = f2bf(v1.x); o1.y = f2bf(v1.y); o1.z = f2bf(v1.z); o1.w = f2bf(v1.w);
  *(ushort4*)(D + (size_t)n * 8) = o0;
  *(ushort4*)(D + (size_t)n * 8 + 4) = o1;
}

__global__ __launch_bounds__(256) void zeroreg(uint4* __restrict__ p) {
  p[blockIdx.x * 256 + threadIdx.x] = uint4{0, 0, 0, 0};
}

// ---------------------------------------------------------------------------
// 128x128 MFMA GEMM: G[r][j] = bias[j] + sum_k A[r][k]*Wb[j][k]. (unchanged)
// ---------------------------------------------------------------------------
__global__ __launch_bounds__(256) void gemm128(
    const float* __restrict__ xA, const ush* __restrict__ Wb,
    const float* __restrict__ bias, float* __restrict__ G, int t0) {
  __shared__ ush As[128][88];
  __shared__ ush Bs[128][88];
  int tid = threadIdx.x;
  int bn = blockIdx.x, bm = blockIdx.y;
  int srow = tid >> 1;
  int shalf = (tid & 1) * 32;
  int lane = tid & 63, quad = lane >> 4, l15 = lane & 15;
  int w = tid >> 6;
  int m_base = (w >> 1) * 64, n_base = (w & 1) * 64;

  int r = bm * 128 + srow;
  const float* axf = xA + ((size_t)(r & 31) * TT + t0 + (r >> 5)) * 1024;
  const ush* wrow = Wb + (size_t)(bn * 128 + srow) * 1024;

  f32x4 acc[4][4];
#pragma unroll
  for (int i = 0; i < 4; ++i)
#pragma unroll
    for (int j = 0; j < 4; ++j) acc[i][j] = f32x4{0.f, 0.f, 0.f, 0.f};

  for (int k0 = 0; k0 < 1024; k0 += 64) {
    {
      const float* p = axf + k0 + shalf;
      ush* d = &As[srow][shalf];
#pragma unroll
      for (int s = 0; s < 8; ++s) {
        float4 v = ((const float4*)p)[s];
        ushort4 o;
        o.x = f2bf(v.x); o.y = f2bf(v.y); o.z = f2bf(v.z); o.w = f2bf(v.w);
        ((ushort4*)d)[s] = o;
      }
    }
    {
      const uint4* p = (const uint4*)(wrow + k0 + shalf);
      uint4* d = (uint4*)&Bs[srow][shalf];
#pragma unroll
      for (int s = 0; s < 4; ++s) d[s] = p[s];
    }
    __syncthreads();
#pragma unroll
    for (int kc = 0; kc < 2; ++kc) {
      bf16x8 af[4], bf_[4];
#pragma unroll
      for (int i = 0; i < 4; ++i)
        af[i] = *(const bf16x8*)&As[m_base + i * 16 + l15][kc * 32 + quad * 8];
#pragma unroll
      for (int j = 0; j < 4; ++j)
        bf_[j] = *(const bf16x8*)&Bs[n_base + j * 16 + l15][kc * 32 + quad * 8];
#pragma unroll
      for (int i = 0; i < 4; ++i)
#pragma unroll
        for (int j = 0; j < 4; ++j)
          acc[i][j] = __builtin_amdgcn_mfma_f32_16x16x32_bf16(af[i], bf_[j],
                                                              acc[i][j], 0, 0, 0);
    }
    __syncthreads();
  }

#pragma unroll
  for (int j = 0; j < 4; ++j) {
    int col = bn * 128 + n_base + j * 16 + l15;
    float bj = bias[col];
#pragma unroll
    for (int i = 0; i < 4; ++i) {
      int row = bm * 128 + m_base + i * 16 + quad * 4;
#pragma unroll
      for (int reg = 0; reg < 4; ++reg)
        G[(size_t)(row + reg) * 4096 + col] = acc[i][j][reg] + bj;
    }
  }
}

// ---------------------------------------------------------------------------
// Persistent flag-synced recurrence for one chunk of Tc steps.
// 160 blocks x 512 thr. flags: prog0 @ flg (64), prog1 @ +1024 (32),
// progP @ +3072 (64).
// ---------------------------------------------------------------------------
__global__ __launch_bounds__(512, 2) void lstm_persist(
    const float* __restrict__ G0, const ush* __restrict__ Wsw0,
    const ush* __restrict__ WswP, const ush* __restrict__ Wsw1n,
    const float* __restrict__ b1,
    ush* __restrict__ h0r, ush* __restrict__ h1r, float* __restrict__ Pr,
    unsigned int* __restrict__ flg,
    float* __restrict__ cst, float* __restrict__ OUT,
    float* __restrict__ hno, float* __restrict__ cno,
    int t0, int Tc, int last) {
  __shared__ ush hbuf[32768];       // 64 KB h staging
  __shared__ float pg[8][32][20];   // padded partial-gate exchange (L0/P only)
  char* hb = (char*)hbuf;

  int tid = threadIdx.x;
  int bid = blockIdx.x;
  int w = tid >> 6, lane = tid & 63, quad = lane >> 4, l15 = lane & 15;
  unsigned int* prog0 = flg;
  unsigned int* prog1 = flg + 1024;
  unsigned int* progP = flg + 3072;

  if (bid < NA) {
    // ================= layer-0 block: 16 cols x 4 gates, K=1024 ============
    int c0 = bid * 16;
    const ush* wp = Wsw0 + ((size_t)bid * 8 + w) * 8192 + (size_t)lane * 8;
    bf16x8 wreg[16];
#pragma unroll
    for (int ch = 0; ch < 16; ++ch) wreg[ch] = *(const bf16x8*)(wp + ch * 512);
#pragma unroll
    for (int ch = 0; ch < 16; ++ch) asm volatile("" : "+v"(wreg[ch]));
    int b = tid >> 4, c = tid & 15;
    int ci = b * 1024 + c0 + c;
    float creg = (t0 > 0) ? cst[ci] : 0.f;
    int mPc = t0;  // cached min(progP) lower bound (wave0)
    int kbase = (w >> 2) * 1024 + quad * 16;
    int x0 = (l15 & 7) << 4;
    const char* a0p = hb + l15 * 2048;
    const char* a1p = hb + (16 + l15) * 2048;

    for (int s = 0; s < Tc; ++s) {
      int t = t0 + s;
      const float* grow = G0 + (size_t)(s * 32 + b) * 4096 + c0 + c;
      float g0v = grow[0], g1v = grow[1024], g2v = grow[2048], g3v = grow[3072];
      if (w == 0) {
        if ((int)aload(&prog0[lane * 16]) < t) {
          do { __builtin_amdgcn_s_sleep(1); } while ((int)aload(&prog0[lane * 16]) < t);
        }
        while (mPc < t - (RING - 1)) {  // h0r clobber guard: P consumers
          int m = (int)aload(&progP[lane * 16]);
#pragma unroll
          for (int d = 1; d < 64; d <<= 1) m = min(m, __shfl_xor(m, d));
          mPc = m;
          if (mPc < t - (RING - 1)) __builtin_amdgcn_s_sleep(2);
        }
      }
      __syncthreads();
      {  // stage h0[t-1]: 16B sc1 loads -> one waitcnt -> b128 LDS writes
        const char* src = (const char*)h0r + (size_t)((t - 1) & (RING - 1)) * 65536;
        i32x4 r_[8];
#pragma unroll
        for (int s2 = 0; s2 < 8; ++s2) {
          int gi = s2 * 512 + tid;
          asm volatile("global_load_dwordx4 %0, %1, off sc1"
                       : "=v"(r_[s2]) : "v"(src + (size_t)gi * 16));
        }
        asm volatile("s_waitcnt vmcnt(0)" ::: "memory");
        __builtin_amdgcn_sched_barrier(0);
#pragma unroll
        for (int s2 = 0; s2 < 8; ++s2) {
          int gi = s2 * 512 + tid;
          int r = gi >> 7, kb = (gi & 127) * 16;
          *(i32x4*)(hb + r * 2048 + (kb ^ ((r & 7) << 4))) = r_[s2];
        }
      }
      __syncthreads();
      f32x4 acc0 = {0.f, 0.f, 0.f, 0.f}, acc1 = {0.f, 0.f, 0.f, 0.f};
#pragma unroll
      for (int ch = 0; ch < 16; ++ch) {
        int kb = kbase + ch * 64;
        bf16x8 a0 = *(const bf16x8*)(a0p + (kb ^ x0));
        bf16x8 a1 = *(const bf16x8*)(a1p + (kb ^ x0));
        acc0 = __builtin_amdgcn_mfma_f32_16x16x32_bf16(a0, wreg[ch], acc0, 0, 0, 0);
        acc1 = __builtin_amdgcn_mfma_f32_16x16x32_bf16(a1, wreg[ch], acc1, 0, 0, 0);
      }
#pragma unroll
      for (int reg = 0; reg < 4; ++reg) {
        pg[w][quad * 4 + reg][l15] = acc0[reg];
        pg[w][16 + quad * 4 + reg][l15] = acc1[reg];
      }
      __syncthreads();
      float s0 = g0v + pg[0][b][c] + pg[4][b][c];
      float s1 = g1v + pg[1][b][c] + pg[5][b][c];
      float s2 = g2v + pg[2][b][c] + pg[6][b][c];
      float s3 = g3v + pg[3][b][c] + pg[7][b][c];
      float fg = sigm(s0), ig = sigm(s1), gv = tanhf(s2), og = sigm(s3);
      creg = fg * creg + ig * gv;
      float hnv = og * tanhf(creg);
      float ho = __shfl_xor(hnv, 1);
      unsigned int pk = (unsigned int)f2bf(hnv) | ((unsigned int)f2bf(ho) << 16);
      unsigned int pk2 = __shfl_xor(pk, 2);
      u64 d0 = (u64)pk | ((u64)pk2 << 32);
      u64 d1 = (u64)__shfl_xor((long long)d0, 4);
      if ((tid & 7) == 0) {
        i32x4 v;
        v.x = (int)d0; v.y = (int)(d0 >> 32);
        v.z = (int)d1; v.w = (int)(d1 >> 32);
        char* dp = (char*)(h0r + (size_t)(t & (RING - 1)) * 32768 +
                           (size_t)b * 1024 + c0 + c);
        asm volatile("global_store_dwordx4 %0, %1, off sc1"
                     :: "v"(dp), "v"(v) : "memory");
      }
      if (t == TT - 1) hno[ci] = hnv;
      asm volatile("s_waitcnt vmcnt(0)" ::: "memory");
      __syncthreads();
      if (tid == 0) astore(&prog0[bid * 16], (unsigned int)(t + 1));
    }
    cst[ci] = creg;
    if (last) cno[ci] = creg;
  } else if (bid < 2 * NA) {
    // ======== P-block: P[t] = W1h0 . h0[t], 16 cols x 4 gates, K=1024 ======
    int p = bid - NA;
    int c0 = p * 16;
    const ush* wp = WswP + ((size_t)p * 8 + w) * 8192 + (size_t)lane * 8;
    bf16x8 wreg[16];
#pragma unroll
    for (int ch = 0; ch < 16; ++ch) wreg[ch] = *(const bf16x8*)(wp + ch * 512);
#pragma unroll
    for (int ch = 0; ch < 16; ++ch) asm volatile("" : "+v"(wreg[ch]));
    int b = tid >> 4, c = tid & 15;
    int m1c = t0;  // cached min(prog1) lower bound (Pr clobber guard)
    int kbase = (w >> 2) * 1024 + quad * 16;
    int x0 = (l15 & 7) << 4;
    const char* a0p = hb + l15 * 2048;
    const char* a1p = hb + (16 + l15) * 2048;

    for (int s = 0; s < Tc; ++s) {
      int t = t0 + s;
      if (w == 0) {
        if ((int)aload(&prog0[lane * 16]) < t + 1) {  // h0[t] ready
          do { __builtin_amdgcn_s_sleep(1); } while ((int)aload(&prog0[lane * 16]) < t + 1);
        }
        while (m1c < t - (RING - 1)) {  // Pr slot guard: L1 consumed t-8
          int m = (lane < 32) ? (int)aload(&prog1[lane * 16]) : 0x7fffffff;
#pragma unroll
          for (int d = 1; d < 64; d <<= 1) m = min(m, __shfl_xor(m, d));
          m1c = m;
          if (m1c < t - (RING - 1)) __builtin_amdgcn_s_sleep(2);
        }
      }
      __syncthreads();
      {  // stage h0[t]
        const char* src = (const char*)h0r + (size_t)(t & (RING - 1)) * 65536;
        i32x4 r_[8];
#pragma unroll
        for (int s2 = 0; s2 < 8; ++s2) {
          int gi = s2 * 512 + tid;
          asm volatile("global_load_dwordx4 %0, %1, off sc1"
                       : "=v"(r_[s2]) : "v"(src + (size_t)gi * 16));
        }
        asm volatile("s_waitcnt vmcnt(0)" ::: "memory");
        __builtin_amdgcn_sched_barrier(0);
#pragma unroll
        for (int s2 = 0; s2 < 8; ++s2) {
          int gi = s2 * 512 + tid;
          int r = gi >> 7, kb = (gi & 127) * 16;
          *(i32x4*)(hb + r * 2048 + (kb ^ ((r & 7) << 4))) = r_[s2];
        }
      }
      __syncthreads();
      f32x4 acc0 = {0.f, 0.f, 0.f, 0.f}, acc1 = {0.f, 0.f, 0.f, 0.f};
#pragma unroll
      for (int ch = 0; ch < 16; ++ch) {
        int kb = kbase + ch * 64;
        bf16x8 a0 = *(const bf16x8*)(a0p + (kb ^ x0));
        bf16x8 a1 = *(const bf16x8*)(a1p + (kb ^ x0));
        acc0 = __builtin_amdgcn_mfma_f32_16x16x32_bf16(a0, wreg[ch], acc0, 0, 0, 0);
        acc1 = __builtin_amdgcn_mfma_f32_16x16x32_bf16(a1, wreg[ch], acc1, 0, 0, 0);
      }
#pragma unroll
      for (int reg = 0; reg < 4; ++reg) {
        pg[w][quad * 4 + reg][l15] = acc0[reg];
        pg[w][16 + quad * 4 + reg][l15] = acc1[reg];
      }
      __syncthreads();
      float s0 = pg[0][b][c] + pg[4][b][c];
      float s1 = pg[1][b][c] + pg[5][b][c];
      float s2 = pg[2][b][c] + pg[6][b][c];
      float s3 = pg[3][b][c] + pg[7][b][c];
      {
        i32x4 v;
        v.x = __float_as_int(s0); v.y = __float_as_int(s1);
        v.z = __float_as_int(s2); v.w = __float_as_int(s3);
        char* dp = (char*)Pr + (size_t)(t & (RING - 1)) * 524288 +
                   (size_t)(b * 1024 + c0 + c) * 16;
        asm volatile("global_store_dwordx4 %0, %1, off sc1"
                     :: "v"(dp), "v"(v) : "memory");
      }
      asm volatile("s_waitcnt vmcnt(0)" ::: "memory");
      __syncthreads();
      if (tid == 0) astore(&progP[p * 16], (unsigned int)(t + 1));
    }
  } else {
    // === layer-1 fat block: 32 cols, per-wave 4 cols x 4 gates, K=1024 =====
    int jb = bid - 2 * NA;          // 0..31
    int c0b = jb * 32;
    const ush* wp = Wsw1n + (size_t)(jb * 8 + w) * 16384 + (size_t)lane * 8;
    bf16x8 wreg[32];
#pragma unroll
    for (int ch = 0; ch < 32; ++ch) wreg[ch] = *(const bf16x8*)(wp + ch * 512);
#pragma unroll
    for (int ch = 0; ch < 32; ++ch) asm volatile("" : "+v"(wreg[ch]));
    int cl = l15 & 3, bq = (l15 >> 2) & 3;
    int col = c0b + w * 4 + cl;
    int ba0 = quad * 4 + bq, ba1 = 16 + quad * 4 + bq;
    int ci0 = ba0 * 1024 + col, ci1 = ba1 * 1024 + col;
    float creg0 = (t0 > 0) ? cst[32768 + ci0] : 0.f;
    float creg1 = (t0 > 0) ? cst[32768 + ci1] : 0.f;
    float biasr[4];
#pragma unroll
    for (int g = 0; g < 4; ++g) biasr[g] = b1[g * 1024 + col];
    int x0 = (l15 & 7) << 4;
    const char* a0p = hb + l15 * 2048;
    const char* a1p = hb + (16 + l15) * 2048;

    for (int s = 0; s < Tc; ++s) {
      int t = t0 + s;
      if (w == 0) {
        if (lane < 2) {  // P[t] for this block's cols (P runs ~8 ahead)
          while ((int)aload(&progP[(2 * jb + lane) * 16]) < t + 1)
            __builtin_amdgcn_s_sleep(1);
        }
        if (lane < 32) {  // h1[t-1]: all 32 L1 blocks done step t-1
          while ((int)aload(&prog1[lane * 16]) < t)
            __builtin_amdgcn_s_sleep(1);
        }
      }
      __syncthreads();
      // issue P loads (16B, 4 gates) + h1 staging loads; one vmcnt
      i32x4 pf0, pf1;
      {
        const char* pps = (const char*)Pr + (size_t)(t & (RING - 1)) * 524288;
        asm volatile("global_load_dwordx4 %0, %1, off sc1"
                     : "=v"(pf0) : "v"(pps + (size_t)ci0 * 16));
        asm volatile("global_load_dwordx4 %0, %1, off sc1"
                     : "=v"(pf1) : "v"(pps + (size_t)ci1 * 16));
      }
      {
        const char* src = (const char*)h1r + (size_t)((t - 1) & (RING - 1)) * 65536;
        i32x4 r1_[8];
#pragma unroll
        for (int s2 = 0; s2 < 8; ++s2) {
          int gi = s2 * 512 + tid;
          asm volatile("global_load_dwordx4 %0, %1, off sc1"
                       : "=v"(r1_[s2]) : "v"(src + (size_t)gi * 16));
        }
        asm volatile("s_waitcnt vmcnt(0)" ::: "memory");
        __builtin_amdgcn_sched_barrier(0);
#pragma unroll
        for (int s2 = 0; s2 < 8; ++s2) {
          int gi = s2 * 512 + tid;
          int r = gi >> 7, kb = (gi & 127) * 16;
          *(i32x4*)(hb + r * 2048 + (kb ^ ((r & 7) << 4))) = r1_[s2];
        }
      }
      __syncthreads();
      f32x4 acc0 = {0.f, 0.f, 0.f, 0.f}, acc1 = {0.f, 0.f, 0.f, 0.f};
#pragma unroll
      for (int ch = 0; ch < 32; ++ch) {
        int kb = ch * 64 + quad * 16;
        bf16x8 a0 = *(const bf16x8*)(a0p + (kb ^ x0));
        bf16x8 a1 = *(const bf16x8*)(a1p + (kb ^ x0));
        acc0 = __builtin_amdgcn_mfma_f32_16x16x32_bf16(a0, wreg[ch], acc0, 0, 0, 0);
        acc1 = __builtin_amdgcn_mfma_f32_16x16x32_bf16(a1, wreg[ch], acc1, 0, 0, 0);
      }
      // 4x4 transpose: lane bits[3:2] (gate) <-> reg; after, reg = gate.
      {
        float t0_, t1_, r0_, r1_;
        if ((bq & 1) == 0) { t0_ = acc0[1]; t1_ = acc0[3]; }
        else               { t0_ = acc0[0]; t1_ = acc0[2]; }
        r0_ = __shfl_xor(t0_, 4); r1_ = __shfl_xor(t1_, 4);
        if ((bq & 1) == 0) { acc0[1] = r0_; acc0[3] = r1_; }
        else               { acc0[0] = r0_; acc0[2] = r1_; }
        if ((bq & 2) == 0) { t0_ = acc0[2]; t1_ = acc0[3]; }
        else               { t0_ = acc0[0]; t1_ = acc0[1]; }
        r0_ = __shfl_xor(t0_, 8); r1_ = __shfl_xor(t1_, 8);
        if ((bq & 2) == 0) { acc0[2] = r0_; acc0[3] = r1_; }
        else               { acc0[0] = r0_; acc0[1] = r1_; }
        if ((bq & 1) == 0) { t0_ = acc1[1]; t1_ = acc1[3]; }
        else               { t0_ = acc1[0]; t1_ = acc1[2]; }
        r0_ = __shfl_xor(t0_, 4); r1_ = __shfl_xor(t1_, 4);
        if ((bq & 1) == 0) { acc1[1] = r0_; acc1[3] = r1_; }
        else               { acc1[0] = r0_; acc1[2] = r1_; }
        if ((bq & 2) == 0) { t0_ = acc1[2]; t1_ = acc1[3]; }
        else               { t0_ = acc1[0]; t1_ = acc1[1]; }
        r0_ = __shfl_xor(t0_, 8); r1_ = __shfl_xor(t1_, 8);
        if ((bq & 2) == 0) { acc1[2] = r0_; acc1[3] = r1_; }
        else               { acc1[0] = r0_; acc1[1] = r1_; }
      }
      float s00 = acc0[0] + __int_as_float(pf0[0]) + biasr[0];
      float s01 = acc0[1] + __int_as_float(pf0[1]) + biasr[1];
      float s02 = acc0[2] + __int_as_float(pf0[2]) + biasr[2];
      float s03 = acc0[3] + __int_as_float(pf0[3]) + biasr[3];
      float s10 = acc1[0] + __int_as_float(pf1[0]) + biasr[0];
      float s11 = acc1[1] + __int_as_float(pf1[1]) + biasr[1];
      float s12 = acc1[2] + __int_as_float(pf1[2]) + biasr[2];
      float s13 = acc1[3] + __int_as_float(pf1[3]) + biasr[3];
      float fg0 = sigm(s00), ig0 = sigm(s01), gg0 = tanhf(s02), og0 = sigm(s03);
      float fg1 = sigm(s10), ig1 = sigm(s11), gg1 = tanhf(s12), og1 = sigm(s13);
      creg0 = fg0 * creg0 + ig0 * gg0;
      creg1 = fg1 * creg1 + ig1 * gg1;
      float h0v = og0 * tanhf(creg0);
      float h1v = og1 * tanhf(creg1);
      // pack 4 cols -> 8B sc1 stores on cl==0 lanes
      unsigned pkA = (unsigned)f2bf(h0v) | ((unsigned)f2bf(__shfl_xor(h0v, 1)) << 16);
      unsigned pkAb = __shfl_xor(pkA, 2);
      unsigned pkB = (unsigned)f2bf(h1v) | ((unsigned)f2bf(__shfl_xor(h1v, 1)) << 16);
      unsigned pkBb = __shfl_xor(pkB, 2);
      if (cl == 0) {
        i32x2 vA; vA[0] = (int)pkA; vA[1] = (int)pkAb;
        char* dpA = (char*)(h1r + (size_t)(t & (RING - 1)) * 32768 +
                            (size_t)ba0 * 1024 + col);
        asm volatile("global_store_dwordx2 %0, %1, off sc1"
                     :: "v"(dpA), "v"(vA) : "memory");
        i32x2 vB; vB[0] = (int)pkB; vB[1] = (int)pkBb;
        char* dpB = (char*)(h1r + (size_t)(t & (RING - 1)) * 32768 +
                            (size_t)ba1 * 1024 + col);
        asm volatile("global_store_dwordx2 %0, %1, off sc1"
                     :: "v"(dpB), "v"(vB) : "memory");
      }
      asm volatile("s_waitcnt vmcnt(0)" ::: "memory");
      __syncthreads();
      if (tid == 0) astore(&prog1[jb * 16], (unsigned int)(t + 1));
      OUT[((size_t)ba0 * TT + t) * 1024 + col] = h0v;   // off critical path
      OUT[((size_t)ba1 * TT + t) * 1024 + col] = h1v;
      if (t == TT - 1) { hno[32768 + ci0] = h0v; hno[32768 + ci1] = h1v; }
    }
    cst[32768 + ci0] = creg0;
    cst[32768 + ci1] = creg1;
    if (last) { cno[32768 + ci0] = creg0; cno[32768 + ci1] = creg1; }
  }
}

extern "C" void kernel_launch(void* const* d_in, const int* in_sizes, int n_in,
                              void* d_out, int out_size, void* d_ws, size_t ws_size,
                              hipStream_t stream) {
  const float* x = (const float*)d_in[0];
  const float* W0 = (const float*)d_in[1];
  const float* b0 = (const float*)d_in[2];
  const float* W1 = (const float*)d_in[3];
  const float* b1 = (const float*)d_in[4];
  float* OUT = (float*)d_out;

  // ws layout (bytes):
  //   Wxb0  [4096][1024] bf16 : 0         (gemm B, x-half of W0)
  //   Wsw0  swizzled 8 MB     : 8388608   (W0 h-half, L0 blocks)
  //   WswP  swizzled 8 MB     : 16777216  (W1 h0-half, P blocks)
  //   Wsw1n swizzled 8 MB     : 25165824  (W1 h1-half, fat L1 blocks)
  //   h0r   RINGx64KB         : 33554432
  //   h1r   RINGx64KB         : 34078720
  //   Pr    RINGx512KB f32    : 34603008
  //   flg   16 KB             : 38797312
  //   cst   [2][32][1024] f32 : 38813696
  //   G0    [Tc*32][4096] f32 : 39075840
  int Tc = 4;
  {
    const int cand[8] = {512, 256, 128, 64, 32, 16, 8, 4};
    for (int i = 0; i < 8; ++i) {
      size_t need = 39075840ull + (size_t)cand[i] * 524288;
      if (need <= ws_size) { Tc = cand[i]; break; }
    }
  }
  char* ws = (char*)d_ws;
  ush* Wxb0 = (ush*)ws;
  ush* Wsw0 = (ush*)(ws + 8388608);
  ush* WswP = (ush*)(ws + 16777216);
  ush* Wsw1n = (ush*)(ws + 25165824);
  ush* h0r = (ush*)(ws + 33554432);
  ush* h1r = (ush*)(ws + 34078720);
  float* Pr = (float*)(ws + 34603008);
  unsigned int* flg = (unsigned int*)(ws + 38797312);
  float* cst = (float*)(ws + 38813696);
  float* G = (float*)(ws + 39075840);

  cast_w1k<<<4096, 256, 0, stream>>>(W0, Wxb0, 0);
  swzW<<<2048, 256, 0, stream>>>(W0, Wsw0, 1024);
  swzW<<<2048, 256, 0, stream>>>(W1, WswP, 0);
  swz1n<<<2048, 256, 0, stream>>>(W1, Wsw1n);
  // zero rings + Pr + flags: 1284 x 4 KB = [33554432, 38813696)
  zeroreg<<<1284, 256, 0, stream>>>((uint4*)(ws + 33554432));

  float* hnp = OUT + 16777216;
  float* cnp = OUT + 16777216 + 65536;
  dim3 ggrid(32, (unsigned)(Tc * 32 / 128));

  const int NCH = TT / Tc;
  for (int ch = 0; ch < NCH; ++ch) {
    int t0v = ch * Tc;
    int lastv = (ch == NCH - 1) ? 1 : 0;
    gemm128<<<ggrid, 256, 0, stream>>>(x, Wxb0, b0, G, t0v);
    void* pargs[16] = {(void*)&G,     (void*)&Wsw0, (void*)&WswP,
                       (void*)&Wsw1n, (void*)&b1,   (void*)&h0r,
                       (void*)&h1r,   (void*)&Pr,   (void*)&flg,
                       (void*)&cst,   (void*)&OUT,  (void*)&hnp,
                       (void*)&cnp,   (void*)&t0v,  (void*)&Tc,
                       (void*)&lastv};
    hipLaunchCooperativeKernel((void*)lstm_persist, dim3(2 * NA + 32), dim3(512),
                               pargs, 0, stream);
  }
}